// Round 12
// baseline (1997.078 us; speedup 1.0000x reference)
//
#include <hip/hip_runtime.h>
#include <math.h>

namespace {

typedef _Float16 f16;
typedef __attribute__((ext_vector_type(8))) _Float16 f16x8;
typedef __attribute__((ext_vector_type(4))) float f32x4;

constexpr int TOK = 4096;
constexpr int DL  = 512;
constexpr int DS  = 128;
constexpr int NC  = 512;
constexpr int NSLOT = 13;

__device__ __forceinline__ float wsum(float v){
  #pragma unroll
  for(int o=32;o>0;o>>=1) v += __shfl_xor(v,o);
  return v;
}

__device__ __forceinline__ void gload16(const void* g, void* l){
  __builtin_amdgcn_global_load_lds(
      (const __attribute__((address_space(1))) unsigned int*)g,
      (__attribute__((address_space(3))) unsigned int*)l, 16, 0, 0);
}

// byte offset of the 16B slot holding (row, 16B-granule g) — bank-spread bijection
__device__ __forceinline__ int slotb(int row, int g){
  return (((row ^ ((row>>2)&1))<<2) | (g ^ (row&3))) << 4;
}

// ===========================================================================
// fp16x2-split MFMA GEMM — SINGLE-WAVE blocks, 64x64 tile per wave.
// Grid (64,8) = 512 blocks, 64 threads each, 2 blocks/CU.
// Why: 4-wave 32x32 tiling re-reads every fragment twice -> 683B LDS/MFMA;
// one wave owning the whole 64x64 tile gets 341B/MFMA (16KB reads / 48 MFMA
// per K-step) AND needs no s_barrier at all — the K-loop self-synchronizes
// via counted vmcnt (stage kt+2's 16 chunks, vmcnt(16) retires kt+1's).
// AMODE: 0 plain
//        1 concat [A1 | slab[gsel[m]]], gsel from FUSED bus-argmax (relmax)
//        2 concat [A1 | cb[gsel[m]]],   gsel from FUSED codemax finalize
// EPI: 0 planes (zread) ; 1 score block-partial argmax (no C write)
//      2 relu planes (hid) ; 3 fp32 + fp32-res (+slab planes via C2) (nodeo)
//      4 fp32 + prompt + planes + slab0 planes (input)
// ===========================================================================
template<int AMODE,int EPI>
__global__ __launch_bounds__(64,2) void mgemm(
    const f16* __restrict__ A1h, const f16* __restrict__ A1l,
    const f16* __restrict__ A2h, const f16* __restrict__ A2l,
    const f16* __restrict__ Bh, const f16* __restrict__ Bl,
    const float* __restrict__ bias, const float* __restrict__ res,
    float* __restrict__ Cf, f16* __restrict__ Ch, f16* __restrict__ Cl,
    f16* __restrict__ C2h, f16* __restrict__ C2l,
    float* __restrict__ scpv, int* __restrict__ scpi, int* __restrict__ idxg,
    const float* __restrict__ relc, const int* __restrict__ msg,
    int* __restrict__ cons, int pt, int node,
    int K, int K0)
{
  constexpr int SMB = 16384;  // A: hi 4K | lo 4K ; B: hi 4K | lo 4K
  __shared__ __align__(16) char smem[3*SMB];
  __shared__ int gsel[64];
  const int l = threadIdx.x;           // 64 threads = 1 wave
  const int m0 = blockIdx.x*64, n0 = blockIdx.y*64;
  const int NK = K>>5, SW = K0>>5;

  // ---- fused bus-argmax (relmax): per-row argmax over snapshot slots ------
  if(AMODE==1){
    {
      int m = m0+l;
      float best = -1e9f; int bs = 0;
      for(int s=0;s<pt;s++){
        float v = msg[s] ? relc[(size_t)((s<<2)+node)*TOK + m] : -1e9f;
        if(v > best){ best=v; bs=s; }
      }
      gsel[l]=bs;
      cons[bs]=1;                      // benign duplicate stores of 1
    }
    __syncthreads();
  }
  // ---- fused code-argmax finalize (reads 8 block-partials, ascending y) ----
  if(AMODE==2){
    {
      int m = m0+l;
      float bv = -INFINITY; int bi = 0;
      #pragma unroll
      for(int y=0;y<8;y++){
        float v = scpv[(size_t)y*TOK + m];
        if(v > bv){ bv=v; bi=scpi[(size_t)y*TOK + m]; }
      }
      gsel[l]=bi;
      idxg[m]=bi;                      // duplicate identical writes across y-blocks
    }
    __syncthreads();
  }

  // ---- per-lane staging decode (inverse of slotb, per 16-row chunk) -------
  // chunk c, lane l fills slot l: global row = 16c + rl, granule g.
  const int rl = (l>>2) ^ ((l>>4)&1);
  const int g8 = ((l&3) ^ (rl&3))<<3;

  // current chunk pointers: cA[0..3] = A hi (rows 16c+rl), cA[4..7] = A lo;
  // cB likewise for B. p2 = part2 (gather) bases for the K0 switch.
  const f16* cA[8]; const f16* cB[8]; const f16* p2[8];
  #pragma unroll
  for(int c=0;c<4;c++){
    cA[c]   = A1h + ((size_t)(m0+16*c+rl)<<9) + g8;
    cA[4+c] = A1l + ((size_t)(m0+16*c+rl)<<9) + g8;
    cB[c]   = Bh + (size_t)(n0+16*c+rl)*K + g8;
    cB[4+c] = Bl + (size_t)(n0+16*c+rl)*K + g8;
  }
  if(AMODE==1){
    #pragma unroll
    for(int c=0;c<4;c++){
      size_t off = ((size_t)gsel[16*c+rl]<<21) + ((size_t)(m0+16*c+rl)<<9) + g8;
      p2[c] = A2h + off; p2[4+c] = A2l + off;
    }
  }
  if(AMODE==2){
    #pragma unroll
    for(int c=0;c<4;c++){
      size_t off = ((size_t)gsel[16*c+rl]<<7) + g8;
      p2[c] = A2h + off; p2[4+c] = A2l + off;
    }
  }

  const int q = l>>4, r = l&15;
  int aoff[4], boff[4];
  #pragma unroll
  for(int i=0;i<4;i++){
    aoff[i] = slotb(16*i + r, q);
    boff[i] = 8192 + slotb(16*i + r, q);
  }

  f32x4 acc1[4][4] = {}, acc2[4][4] = {};

  auto advance = [&](int snext){
    #pragma unroll
    for(int c=0;c<8;c++){
      if(AMODE!=0 && snext==SW) cA[c] = p2[c];
      else                      cA[c] += 32;
    }
    #pragma unroll
    for(int c=0;c<8;c++) cB[c] += 32;
  };
  auto stage = [&](int buf){
    char* dst = smem + buf*SMB;
    #pragma unroll
    for(int c=0;c<8;c++){
      int lo = (c<4) ? c*1024 : 4096 + (c-4)*1024;
      gload16(cA[c], dst + lo);
    }
    #pragma unroll
    for(int c=0;c<8;c++){
      int lo = 8192 + ((c<4) ? c*1024 : 4096 + (c-4)*1024);
      gload16(cB[c], dst + lo);
    }
  };

  // ---- prologue: stage steps 0,1 (32 loads); vmcnt(16) -> step-0 complete --
  stage(0); advance(1);
  stage(1); advance(2);
  asm volatile("s_waitcnt vmcnt(16)" ::: "memory");

  int rb = 0;
  for(int kt=0; kt<NK; ++kt){
    const char* Lb = smem + rb*SMB;
    f16x8 bh[4], bl[4];
    #pragma unroll
    for(int j=0;j<4;j++){
      bh[j] = *(const f16x8*)(Lb + boff[j]);
      bl[j] = *(const f16x8*)(Lb + 4096 + boff[j]);
    }
    if(kt+2 < NK){
      int sb = rb+2; if(sb>=3) sb-=3;
      stage(sb); advance(kt+3);
    }
    #pragma unroll
    for(int i=0;i<4;i++){
      f16x8 ah = *(const f16x8*)(Lb + aoff[i]);
      f16x8 al = *(const f16x8*)(Lb + 4096 + aoff[i]);
      #pragma unroll
      for(int j=0;j<4;j++){
        acc1[i][j] = __builtin_amdgcn_mfma_f32_16x16x32_f16(ah, bh[j], acc1[i][j], 0,0,0);
        acc2[i][j] = __builtin_amdgcn_mfma_f32_16x16x32_f16(ah, bl[j], acc2[i][j], 0,0,0);
        acc2[i][j] = __builtin_amdgcn_mfma_f32_16x16x32_f16(al, bh[j], acc2[i][j], 0,0,0);
      }
    }
    // single wave: no barrier — counted vmcnt retires step kt+1's 16 loads,
    // leaving step kt+2's 16 in flight.
    if(kt+2 < NK){ asm volatile("s_waitcnt vmcnt(16)" ::: "memory"); }
    else if(kt+1 < NK){ asm volatile("s_waitcnt vmcnt(0)" ::: "memory"); }
    rb = (rb==2)? 0 : rb+1;
  }

  if(EPI!=1){
    #pragma unroll
    for(int i=0;i<4;i++)
      #pragma unroll
      for(int j=0;j<4;j++)
        #pragma unroll
        for(int rr=0;rr<4;rr++){
          int rowm = m0 + 16*i + 4*q + rr;
          int coln = n0 + 16*j + r;
          size_t o = ((size_t)rowm<<9) + coln;
          float v = acc1[i][j][rr] + acc2[i][j][rr]*(1.0f/2048.0f) + bias[coln];
          if(EPI==2) v = fmaxf(v, 0.f);
          if(EPI==3) v += res[o];
          if(EPI==4) v += res[(((size_t)(rowm&255))<<9) + coln];
          if(EPI==3 || EPI==4) Cf[o] = v;
          if(EPI==0 || EPI==2 || EPI==4){
            f16 h = (f16)v;
            Ch[o] = h; Cl[o] = (f16)((v-(float)h)*2048.0f);
          }
          if((EPI==3 || EPI==4) && C2h){
            f16 h = (f16)v;
            C2h[o] = h; C2l[o] = (f16)((v-(float)h)*2048.0f);
          }
        }
  } else {
    // block-partial argmax over this block's 64 cols, exact first-index ties:
    // j ascending in-lane, then 16-lane shfl within the q-group.
    #pragma unroll
    for(int i=0;i<4;i++)
      #pragma unroll
      for(int rr=0;rr<4;rr++){
        float bv = -INFINITY; int bc = 0;
        #pragma unroll
        for(int j=0;j<4;j++){
          float v = acc1[i][j][rr] + acc2[i][j][rr]*(1.0f/2048.0f) + bias[n0+16*j+r];
          int c = n0 + 16*j + r;
          if(v > bv){ bv=v; bc=c; }
        }
        #pragma unroll
        for(int o=1;o<16;o<<=1){
          float ov = __shfl_xor(bv,o); int oi = __shfl_xor(bc,o);
          if(ov>bv || (ov==bv && oi<bc)){ bv=ov; bc=oi; }
        }
        if(r==0){
          int rowm = m0 + 16*i + 4*q + rr;
          scpv[(size_t)blockIdx.y*TOK + rowm] = bv;
          scpi[(size_t)blockIdx.y*TOK + rowm] = bc;
        }
      }
  }
}

// --- fp32 -> (hi, lo*2048) split -------------------------------------------
__global__ void split_k(const float* __restrict__ src, f16* __restrict__ hi,
                        f16* __restrict__ lo, int n){
  for(int i = blockIdx.x*256 + threadIdx.x; i < n; i += gridDim.x*256){
    float v = src[i];
    f16 h = (f16)v;
    hi[i] = h;
    lo[i] = (f16)((v - (float)h)*2048.0f);
  }
}

// --- batched weight split: 5 segments in one dispatch ----------------------
struct SplitArg { const float* src; f16* hi; f16* lo; int n; };
struct SplitArgs5 { SplitArg a[5]; };
__global__ void splitm_k(SplitArgs5 A){
  int stride = gridDim.x*256;
  #pragma unroll
  for(int s=0;s<5;s++){
    const float* src = A.a[s].src; f16* hi = A.a[s].hi; f16* lo = A.a[s].lo;
    int n = A.a[s].n;
    for(int i = blockIdx.x*256 + threadIdx.x; i < n; i += stride){
      float v = src[i];
      f16 h = (f16)v;
      hi[i] = h;
      lo[i] = (f16)((v - (float)h)*2048.0f);
    }
  }
}

// --- wcomb[n*512+c][l] = sum_d cb[n][c][d] * sym_w[n][d][l]  (fp32, small) --
__global__ __launch_bounds__(256)
void wcomb_k(const float* __restrict__ A, const float* __restrict__ Wall,
             float* __restrict__ C)
{
  constexpr int T=256;
  __shared__ float As[32][68];
  __shared__ float Ws[32][132];
  const int tid = threadIdx.x;
  const int m0 = blockIdx.x*64, n0 = blockIdx.y*128;
  const float* W = Wall + (size_t)(m0>>9)*DS*DL;
  const int ty = tid>>4, tx = tid&15;
  float4 pa[2], pw[4];
  auto loadA = [&](int k0){
    #pragma unroll
    for(int it=0; it<2; ++it){
      int v = tid + T*it; int rr = v>>3, c4 = v&7;
      pa[it] = *(const float4*)(A + (size_t)(m0+rr)*DS + k0 + (c4<<2));
    }
  };
  auto loadW = [&](int k0){
    #pragma unroll
    for(int it=0; it<4; ++it){
      int v = tid + T*it; int rr = v>>5, c4 = v&31;
      pw[it] = *(const float4*)(W + (size_t)(k0+rr)*DL + n0 + (c4<<2));
    }
  };
  float acc[4][8];
  #pragma unroll
  for(int i=0;i<4;i++)
    #pragma unroll
    for(int j=0;j<8;j++) acc[i][j]=0.f;
  loadA(0); loadW(0);
  for(int k0=0; k0<DS; k0+=32){
    __syncthreads();
    #pragma unroll
    for(int it=0; it<2; ++it){
      int v = tid + T*it; int rr=v>>3, c4=v&7;
      As[(c4<<2)+0][rr]=pa[it].x; As[(c4<<2)+1][rr]=pa[it].y;
      As[(c4<<2)+2][rr]=pa[it].z; As[(c4<<2)+3][rr]=pa[it].w;
    }
    #pragma unroll
    for(int it=0; it<4; ++it){
      int v = tid + T*it; int rr=v>>5, c4=v&31;
      *(float4*)&Ws[rr][c4<<2] = pw[it];
    }
    __syncthreads();
    if(k0+32 < DS){ loadA(k0+32); loadW(k0+32); }
    #pragma unroll
    for(int kk=0; kk<32; kk++){
      float4 a4 = *(const float4*)&As[kk][ty<<2];
      float4 b0 = *(const float4*)&Ws[kk][tx<<2];
      float4 b1 = *(const float4*)&Ws[kk][64+(tx<<2)];
      float a[4]={a4.x,a4.y,a4.z,a4.w};
      float b[8]={b0.x,b0.y,b0.z,b0.w,b1.x,b1.y,b1.z,b1.w};
      #pragma unroll
      for(int i=0;i<4;i++)
        #pragma unroll
        for(int j=0;j<8;j++) acc[i][j] = fmaf(a[i], b[j], acc[i][j]);
    }
  }
  #pragma unroll
  for(int i=0;i<4;i++){
    int m = m0 + (ty<<2) + i;
    #pragma unroll
    for(int j=0;j<8;j++){
      int n = n0 + ((j<4)? (tx<<2)+j : 64+(tx<<2)+(j-4));
      C[((size_t)m<<9)+n] = acc[i][j];
    }
  }
}

// --- init: active=1, msg={1,0..}, cons=0, relc slot0 = qry_b ---------------
__global__ void init_k(int* __restrict__ msg, int* __restrict__ act,
                       float* __restrict__ relc, const float* __restrict__ qb,
                       int* __restrict__ cons){
  int i = blockIdx.x*256 + threadIdx.x;
  if(i < TOK){
    act[i] = 1;
    #pragma unroll
    for(int nn=0;nn<4;nn++) relc[nn*TOK + i] = qb[nn];
  }
  if(i < 32){ msg[i] = (i==0) ? 1 : 0; cons[i] = 0; }
}

// --- combined quantizer bias: b2 = sym_b.cb - 0.5|cb|^2 --------------------
__global__ void bias2_k(const float* __restrict__ cb, const float* __restrict__ sb,
                        float* __restrict__ b2){
  int row = blockIdx.x*4 + (threadIdx.x>>6);
  int lane = threadIdx.x&63;
  const float* cv = cb + ((size_t)row<<7);
  const float* sbn = sb + ((row>>9)<<7);
  float c0=cv[lane], c1=cv[lane+64];
  float nrm = c0*c0 + c1*c1;
  float dt  = c0*sbn[lane] + c1*sbn[lane+64];
  nrm = wsum(nrm); dt = wsum(dt);
  if(lane==0) b2[row] = dt - 0.5f*nrm;
}

// --- halting / update / rel-cache append / mask-fold -----------------------
__global__ void mupdate_k(const float* __restrict__ no_, float* __restrict__ out,
                          f16* __restrict__ outh, f16* __restrict__ outl,
                          float* __restrict__ relc, const int* __restrict__ idx,
                          const float* __restrict__ cbn, const float* __restrict__ qw,
                          const float* __restrict__ qb, int* __restrict__ act,
                          int* __restrict__ cons, int* __restrict__ msg,
                          int t, int ptr, int pe){
  int m = blockIdx.x*4 + (threadIdx.x>>6);
  int lane = threadIdx.x&63;
  const float* nrow = no_ + ((size_t)m<<9);
  float* orow = out + ((size_t)m<<9);
  float nv[8]; float s=0.f;
  #pragma unroll
  for(int rr=0;rr<8;rr++){
    int c = lane + (rr<<6);
    nv[rr]=nrow[c];
    float d = nv[rr]-orow[c]; s += d*d;
  }
  s = wsum(s);
  float delta = sqrtf(s);
  int a = act[m];
  int halt = (delta < 1e-3f) && a;
  int assigned = (t>0) ? a : 1;
  int upd = assigned && !halt;
  if(lane==0) act[m] = a && !halt;
  if(upd){
    #pragma unroll
    for(int rr=0;rr<8;rr++){
      int c = lane + (rr<<6);
      float v = nv[rr];
      orow[c] = v;
      f16 h = (f16)v;
      outh[((size_t)m<<9)+c] = h;
      outl[((size_t)m<<9)+c] = (f16)((v-(float)h)*2048.0f);
    }
  }
  if(ptr >= 0){
    const float* qv = cbn + ((size_t)idx[m]<<7);
    float q0=qv[lane], q1=qv[lane+64];
    #pragma unroll
    for(int nn=0;nn<4;nn++){
      float pr = q0*qw[(nn<<7)+lane] + q1*qw[(nn<<7)+64+lane];
      pr = wsum(pr);
      if(lane==0) relc[(size_t)((ptr<<2)+nn)*TOK + m] = pr + qb[nn];
    }
  }
  if(pe >= 0 && blockIdx.x==0 && threadIdx.x < 32){
    int s2 = threadIdx.x;
    msg[s2] = (s2 < pe) && !cons[s2];
    cons[s2] = 0;
  }
}

} // namespace

extern "C" void kernel_launch(void* const* d_in, const int* in_sizes, int n_in,
                              void* d_out, int out_size, void* d_ws, size_t ws_size,
                              hipStream_t stream)
{
  (void)in_sizes; (void)n_in; (void)out_size; (void)ws_size;
  const float* x   = (const float*)d_in[0];
  const float* ipw = (const float*)d_in[1];
  const float* ipb = (const float*)d_in[2];
  const float* tp  = (const float*)d_in[3];
  const float* sw  = (const float*)d_in[4];
  const float* sb  = (const float*)d_in[5];
  const float* qw  = (const float*)d_in[6];
  const float* qb  = (const float*)d_in[7];
  const float* rw  = (const float*)d_in[8];
  const float* rb  = (const float*)d_in[9];
  const float* c1w = (const float*)d_in[10];
  const float* c1b = (const float*)d_in[11];
  const float* c2w = (const float*)d_in[12];
  const float* c2b = (const float*)d_in[13];
  const float* cb  = (const float*)d_in[14];
  float* out = (float*)d_out;

  char* p = (char*)d_ws;
  auto alloc = [&](size_t b)->char*{ char* r=p; p += (b+255)&~(size_t)255; return r; };
  f16* slabh = (f16*)alloc((size_t)NSLOT*TOK*DL*2);
  f16* slabl = (f16*)alloc((size_t)NSLOT*TOK*DL*2);
  f16* outh  = (f16*)alloc((size_t)TOK*DL*2);
  f16* outl  = (f16*)alloc((size_t)TOK*DL*2);
  f16* zh    = (f16*)alloc((size_t)TOK*DL*2);
  f16* zl    = (f16*)alloc((size_t)TOK*DL*2);
  f16* hh    = (f16*)alloc((size_t)TOK*DL*2);
  f16* hl    = (f16*)alloc((size_t)TOK*DL*2);
  float* sn  = (float*)alloc((size_t)TOK*DL*4);      // nodeo fp32 + wcomb staging
  f16* rwh   = (f16*)alloc((size_t)4*DL*1024*2);
  f16* rwl   = (f16*)alloc((size_t)4*DL*1024*2);
  f16* c1h   = (f16*)alloc((size_t)4*DL*640*2);
  f16* c1l   = (f16*)alloc((size_t)4*DL*640*2);
  f16* c2h   = (f16*)alloc((size_t)4*DL*DL*2);
  f16* c2l   = (f16*)alloc((size_t)4*DL*DL*2);
  f16* wch   = (f16*)alloc((size_t)4*NC*DL*2);
  f16* wcl   = (f16*)alloc((size_t)4*NC*DL*2);
  f16* iph   = (f16*)alloc((size_t)DL*DL*2);
  f16* ipl   = (f16*)alloc((size_t)DL*DL*2);
  f16* cbh   = (f16*)alloc((size_t)4*NC*DS*2);
  f16* cbl   = (f16*)alloc((size_t)4*NC*DS*2);
  float* b2  = (float*)alloc(4*NC*4);
  float* relc= (float*)alloc((size_t)NSLOT*4*TOK*4);
  float* scpv= (float*)alloc((size_t)8*TOK*4);
  int* scpi  = (int*)alloc((size_t)8*TOK*4);
  int* idxb  = (int*)alloc(TOK*4);
  int* act   = (int*)alloc(TOK*4);
  int* msg   = (int*)alloc(256);
  int* cons  = (int*)alloc(256);

  dim3 G(64,8), B(256), Bm(64);

  init_k<<<16,256,0,stream>>>(msg, act, relc, qb, cons);
  bias2_k<<<512,256,0,stream>>>(cb, sb, b2);
  wcomb_k<<<dim3(32,4),B,0,stream>>>(cb, sw, sn);
  split_k<<<2048,256,0,stream>>>(x, hh, hl, TOK*DL);   // x planes staged in hh/hl
  SplitArgs5 sa;
  sa.a[0] = { ipw, iph, ipl, DL*DL };
  sa.a[1] = { rw,  rwh, rwl, 4*DL*1024 };
  sa.a[2] = { c1w, c1h, c1l, 4*DL*640 };
  sa.a[3] = { c2w, c2h, c2l, 4*DL*DL };
  sa.a[4] = { cb,  cbh, cbl, 4*NC*DS };
  splitm_k<<<2048,256,0,stream>>>(sa);
  split_k<<<1024,256,0,stream>>>(sn, wch, wcl, 4*NC*DL);

  // input projection + prompts -> out(fp32)+planes, slab slot0 planes
  mgemm<0,4><<<G,Bm,0,stream>>>(hh,hl, nullptr,nullptr, iph,ipl,
      ipb, tp, out, outh,outl, slabh,slabl,
      nullptr,nullptr,nullptr, nullptr,nullptr,nullptr, 0,0, DL, DL);

  int ptr = 1;
  for(int t=0;t<4;t++){
    int pt = 1 + 4*t;
    for(int n=0;n<4;n++){
      // z_read = [out | slab[top]] @ read_w^T + read_b   (fused relmax)
      mgemm<1,0><<<G,Bm,0,stream>>>(outh,outl, slabh,slabl,
          rwh+(size_t)n*DL*1024, rwl+(size_t)n*DL*1024, rb+(size_t)n*DL,
          nullptr, nullptr, zh,zl, nullptr,nullptr,
          nullptr,nullptr,nullptr, relc, msg, cons, pt, n, 1024, 512);
      // scores -> block-partial argmax (fused codemax part 1)
      mgemm<0,1><<<G,Bm,0,stream>>>(zh,zl, nullptr,nullptr,
          wch+(size_t)n*NC*DL, wcl+(size_t)n*NC*DL, b2+(size_t)n*NC,
          nullptr, nullptr, nullptr,nullptr, nullptr,nullptr,
          scpv,scpi,nullptr, nullptr,nullptr,nullptr, 0,0, 512, 512);
      // hid = relu([z_read | cb[idx]] @ c1_w^T + c1_b)  (fused codemax finalize)
      mgemm<2,2><<<G,Bm,0,stream>>>(zh,zl, cbh+(size_t)n*NC*DS, cbl+(size_t)n*NC*DS,
          c1h+(size_t)n*DL*640, c1l+(size_t)n*DL*640, c1b+(size_t)n*DL,
          nullptr, nullptr, hh,hl, nullptr,nullptr,
          scpv,scpi,idxb, nullptr,nullptr,nullptr, 0,0, 640, 512);
      // node_out = hid @ c2_w^T + c2_b + out ; slab planes via C2 (t<3)
      f16* sph = (t<3) ? slabh + ((size_t)ptr<<21) : nullptr;
      f16* spl = (t<3) ? slabl + ((size_t)ptr<<21) : nullptr;
      mgemm<0,3><<<G,Bm,0,stream>>>(hh,hl, nullptr,nullptr,
          c2h+(size_t)n*DL*DL, c2l+(size_t)n*DL*DL, c2b+(size_t)n*DL,
          out, sn, nullptr,nullptr, sph,spl,
          nullptr,nullptr,nullptr, nullptr,nullptr,nullptr, 0,0, 512, 512);
      // halting / selective update / rel cache / mask fold
      mupdate_k<<<1024,256,0,stream>>>(sn, out, outh,outl, relc, idxb,
          cb+(size_t)n*NC*DS, qw, qb, act, cons, msg, t,
          (t<3)? ptr : -1, (n==3 && t<3)? (1+4*(t+1)) : -1);
      ptr++;
    }
  }
}

// Round 13
// 1318.940 us; speedup vs baseline: 1.5142x; 1.5142x over previous
//
#include <hip/hip_runtime.h>
#include <math.h>

namespace {

typedef _Float16 f16;
typedef __attribute__((ext_vector_type(8))) _Float16 f16x8;
typedef __attribute__((ext_vector_type(4))) float f32x4;

constexpr int TOK = 4096;
constexpr int DL  = 512;
constexpr int DS  = 128;
constexpr int NC  = 512;
constexpr int NSLOT = 13;

__device__ __forceinline__ float wsum(float v){
  #pragma unroll
  for(int o=32;o>0;o>>=1) v += __shfl_xor(v,o);
  return v;
}

__device__ __forceinline__ void gload16(const void* g, void* l){
  __builtin_amdgcn_global_load_lds(
      (const __attribute__((address_space(1))) unsigned int*)g,
      (__attribute__((address_space(3))) unsigned int*)l, 16, 0, 0);
}

// byte offset of the 16B slot holding (row, 16B-granule g) — bank-spread bijection
__device__ __forceinline__ int slotb(int row, int g){
  return (((row ^ ((row>>2)&1))<<2) | (g ^ (row&3))) << 4;
}

// ===========================================================================
// fp16x2-split MFMA GEMM, BM=64 BN=64 BK=32, 4 waves (each a 32x32 tile).
// Grid (64,8), 2 blocks/CU. 3-buffer pipeline, counted s_waitcnt vmcnt(4).
// (Round-8 kernel; the slab gather has been moved OUT into buspack_k, so
// AMODE 1's part2 is now a CONTIGUOUS busctx plane — plain streaming.)
// AMODE: 0 plain
//        1 concat [A1 | A2[m]] with contiguous A2 (row stride 512)
//        2 concat [A1 | cb[gsel[m]]], gsel from FUSED codemax finalize
// EPI: 0 planes (zread) ; 1 score block-partial argmax (no C write)
//      2 relu planes (hid) ; 3 fp32 + fp32-res (+slab planes via C2) (nodeo)
//      4 fp32 + prompt + planes + slab0 planes (input)
// ===========================================================================
template<int AMODE,int EPI>
__global__ __launch_bounds__(256,2) void mgemm(
    const f16* __restrict__ A1h, const f16* __restrict__ A1l,
    const f16* __restrict__ A2h, const f16* __restrict__ A2l,
    const f16* __restrict__ Bh, const f16* __restrict__ Bl,
    const float* __restrict__ bias, const float* __restrict__ res,
    float* __restrict__ Cf, f16* __restrict__ Ch, f16* __restrict__ Cl,
    f16* __restrict__ C2h, f16* __restrict__ C2l,
    float* __restrict__ scpv, int* __restrict__ scpi, int* __restrict__ idxg,
    int K, int K0)
{
  constexpr int SMB = 16384;  // Ah 4K | Al 4K | Bh 4K | Bl 4K
  __shared__ __align__(16) char smem[3*SMB];
  __shared__ int gsel[64];
  __shared__ float redv[4][32];
  __shared__ int   redi[4][32];
  const int tid = threadIdx.x, w = tid>>6, l = tid&63;
  const int m0 = blockIdx.x*64, n0 = blockIdx.y*64;
  const int NK = K>>5, SW = K0>>5;

  // ---- fused code-argmax finalize (reads 8 block-partials, ascending y) ----
  if(AMODE==2){
    if(tid<64){
      int m = m0+tid;
      float bv = -INFINITY; int bi = 0;
      #pragma unroll
      for(int y=0;y<8;y++){
        float v = scpv[(size_t)y*TOK + m];
        if(v > bv){ bv=v; bi=scpi[(size_t)y*TOK + m]; }
      }
      gsel[tid]=bi;
      idxg[m]=bi;                      // duplicate identical writes across y-blocks
    }
    __syncthreads();
  }

  // ---- staging setup: 16 chunks of 1KB per K-step; wave w owns [4w,4w+4) ---
  const f16* sp[4]; const f16* sp2[4]; int loff[4];
  #pragma unroll
  for(int i=0;i<4;i++){
    int c = 4*w+i;
    int isA = (c<8);
    int plane = isA ? (c>>2) : ((c-8)>>2);
    int cidx  = isA ? (c&3)  : ((c-8)&3);
    loff[i] = (isA?0:8192) + plane*4096 + cidx*1024;
    int s = (cidx<<6) + l;
    int rp = s>>2, row = rp ^ ((rp>>2)&1), g = (s&3) ^ (row&3);  // inverse slotb
    int g8 = g<<3;
    if(isA){
      int m = m0 + row;
      const f16* p1 = (plane? A1l : A1h) + ((size_t)m<<9) + g8;
      sp[i] = p1;
      if(AMODE==1)      sp2[i] = (plane? A2l : A2h) + ((size_t)m<<9) + g8;
      else if(AMODE==2) sp2[i] = (plane? A2l : A2h) + ((size_t)gsel[row]<<7) + g8;
      else              sp2[i] = p1;
    } else {
      sp[i] = (plane? Bl : Bh) + (size_t)(n0+row)*K + g8;
      sp2[i] = sp[i];
    }
  }

  const int wr = w>>1, wc = w&1, q = l>>4, r = l&15;
  int aoff[2], boff[2];
  #pragma unroll
  for(int i=0;i<2;i++) aoff[i] = slotb(32*wr + 16*i + r, q);
  #pragma unroll
  for(int j=0;j<2;j++) boff[j] = 8192 + slotb(32*wc + 16*j + r, q);

  f32x4 acc1[2][2] = {}, acc2[2][2] = {};

  // advance staging pointers to step snext (handles part1->part2 switch)
  auto advance = [&](int snext){
    #pragma unroll
    for(int i=0;i<4;i++){
      if(AMODE!=0 && (4*w+i)<8 && snext==SW) sp[i] = sp2[i];
      else                                    sp[i] += 32;
    }
  };

  // ---- prologue: stage steps 0 and 1 (NK >= 16 always here) ----
  #pragma unroll
  for(int i=0;i<4;i++) gload16(sp[i], smem + loff[i]);
  advance(1);
  #pragma unroll
  for(int i=0;i<4;i++) gload16(sp[i], smem + SMB + loff[i]);
  advance(2);
  asm volatile("s_waitcnt vmcnt(4)" ::: "memory");   // step-0 loads done
  __builtin_amdgcn_s_barrier();

  int roff = 0, soff = 2*SMB;
  for(int kt=0; kt<NK; ++kt){
    const char* Lb = smem + roff;
    f16x8 ah[2], al[2], bh[2], bl[2];
    #pragma unroll
    for(int i=0;i<2;i++){
      ah[i] = *(const f16x8*)(Lb + aoff[i]);
      al[i] = *(const f16x8*)(Lb + 4096 + aoff[i]);
    }
    #pragma unroll
    for(int j=0;j<2;j++){
      bh[j] = *(const f16x8*)(Lb + boff[j]);
      bl[j] = *(const f16x8*)(Lb + 4096 + boff[j]);
    }
    if(kt+2 < NK){
      #pragma unroll
      for(int i=0;i<4;i++) gload16(sp[i], smem + soff + loff[i]);
      advance(kt+3);
    }
    #pragma unroll
    for(int i=0;i<2;i++)
      #pragma unroll
      for(int j=0;j<2;j++){
        acc1[i][j] = __builtin_amdgcn_mfma_f32_16x16x32_f16(ah[i], bh[j], acc1[i][j], 0,0,0);
        acc2[i][j] = __builtin_amdgcn_mfma_f32_16x16x32_f16(ah[i], bl[j], acc2[i][j], 0,0,0);
        acc2[i][j] = __builtin_amdgcn_mfma_f32_16x16x32_f16(al[i], bh[j], acc2[i][j], 0,0,0);
      }
    if(kt+2 < NK){
      asm volatile("s_waitcnt vmcnt(4)" ::: "memory");
      __builtin_amdgcn_s_barrier();
    } else if(kt+1 < NK){
      asm volatile("s_waitcnt vmcnt(0)" ::: "memory");  // tail: drain last stage
      __builtin_amdgcn_s_barrier();
    }
    roff = (roff==2*SMB)? 0 : roff+SMB;
    soff = (soff==2*SMB)? 0 : soff+SMB;
  }

  if(EPI!=1){
    #pragma unroll
    for(int i=0;i<2;i++)
      #pragma unroll
      for(int j=0;j<2;j++)
        #pragma unroll
        for(int rr=0;rr<4;rr++){
          int rowm = m0 + 32*wr + 16*i + 4*q + rr;
          int coln = n0 + 32*wc + 16*j + r;
          size_t o = ((size_t)rowm<<9) + coln;
          float v = acc1[i][j][rr] + acc2[i][j][rr]*(1.0f/2048.0f) + bias[coln];
          if(EPI==2) v = fmaxf(v, 0.f);
          if(EPI==3) v += res[o];
          if(EPI==4) v += res[(((size_t)(rowm&255))<<9) + coln];
          if(EPI==3 || EPI==4) Cf[o] = v;
          if(EPI==0 || EPI==2 || EPI==4){
            f16 h = (f16)v;
            Ch[o] = h; Cl[o] = (f16)((v-(float)h)*2048.0f);
          }
          if((EPI==3 || EPI==4) && C2h){
            f16 h = (f16)v;
            C2h[o] = h; C2l[o] = (f16)((v-(float)h)*2048.0f);
          }
        }
  } else {
    // block-partial argmax over this block's 64 cols, exact first-index ties
    #pragma unroll
    for(int i=0;i<2;i++)
      #pragma unroll
      for(int rr=0;rr<4;rr++){
        float v0 = acc1[i][0][rr] + acc2[i][0][rr]*(1.0f/2048.0f) + bias[n0+32*wc+r];
        float v1 = acc1[i][1][rr] + acc2[i][1][rr]*(1.0f/2048.0f) + bias[n0+32*wc+16+r];
        float bv; int bc;
        if(v1 > v0){ bv=v1; bc=n0+32*wc+16+r; } else { bv=v0; bc=n0+32*wc+r; }
        #pragma unroll
        for(int o=1;o<16;o<<=1){
          float ov = __shfl_xor(bv,o); int oi = __shfl_xor(bc,o);
          if(ov>bv || (ov==bv && oi<bc)){ bv=ov; bc=oi; }
        }
        if(r==0){ redv[w][16*i+4*q+rr]=bv; redi[w][16*i+4*q+rr]=bc; }
      }
    __syncthreads();
    if(tid<64){
      int wr2 = tid>>5, li = tid&31;
      float bv = redv[2*wr2][li]; int bc = redi[2*wr2][li];
      float ov = redv[2*wr2+1][li]; int oi = redi[2*wr2+1][li];
      if(ov>bv || (ov==bv && oi<bc)){ bv=ov; bc=oi; }
      scpv[(size_t)blockIdx.y*TOK + m0 + tid] = bv;
      scpi[(size_t)blockIdx.y*TOK + m0 + tid] = bc;
    }
  }
}

// --- per-op bus pack: all 4 nodes' argmax + gather into contiguous planes --
// One wave per token. High TLP turns the latency-bound L3/HBM gather into a
// bandwidth-bound streaming copy (it was 16x ~15us inside the zread GEMMs).
__global__ __launch_bounds__(256) void buspack_k(
    const float* __restrict__ relc, const int* __restrict__ msg,
    const f16* __restrict__ slabh, const f16* __restrict__ slabl,
    f16* __restrict__ bch, f16* __restrict__ bcl,
    int* __restrict__ cons, int pt)
{
  int w = threadIdx.x>>6, l = threadIdx.x&63;
  int m = blockIdx.x*4 + w;
  int nn = l&3;
  float best = -1e9f; int bs = 0;
  for(int s=0;s<pt;s++){
    float v = msg[s] ? relc[(size_t)((s<<2)+nn)*TOK + m] : -1e9f;
    if(v > best){ best=v; bs=s; }
  }
  int tn[4];
  tn[0] = __shfl(bs,0); tn[1] = __shfl(bs,1);
  tn[2] = __shfl(bs,2); tn[3] = __shfl(bs,3);
  if(l<4) cons[bs] = 1;              // lane n holds node n's top; benign dups
  #pragma unroll
  for(int n2=0;n2<4;n2++){
    size_t so = ((size_t)tn[n2]<<21) + ((size_t)m<<9) + (size_t)(l<<3);
    size_t dofs = ((size_t)n2*TOK<<9) + ((size_t)m<<9) + (size_t)(l<<3);
    *(float4*)&bch[dofs] = *(const float4*)&slabh[so];
    *(float4*)&bcl[dofs] = *(const float4*)&slabl[so];
  }
}

// --- fp32 -> (hi, lo*2048) split -------------------------------------------
__global__ void split_k(const float* __restrict__ src, f16* __restrict__ hi,
                        f16* __restrict__ lo, int n){
  for(int i = blockIdx.x*256 + threadIdx.x; i < n; i += gridDim.x*256){
    float v = src[i];
    f16 h = (f16)v;
    hi[i] = h;
    lo[i] = (f16)((v - (float)h)*2048.0f);
  }
}

// --- batched weight split: 5 segments in one dispatch ----------------------
struct SplitArg { const float* src; f16* hi; f16* lo; int n; };
struct SplitArgs5 { SplitArg a[5]; };
__global__ void splitm_k(SplitArgs5 A){
  int stride = gridDim.x*256;
  #pragma unroll
  for(int s=0;s<5;s++){
    const float* src = A.a[s].src; f16* hi = A.a[s].hi; f16* lo = A.a[s].lo;
    int n = A.a[s].n;
    for(int i = blockIdx.x*256 + threadIdx.x; i < n; i += stride){
      float v = src[i];
      f16 h = (f16)v;
      hi[i] = h;
      lo[i] = (f16)((v - (float)h)*2048.0f);
    }
  }
}

// --- wcomb[n*512+c][l] = sum_d cb[n][c][d] * sym_w[n][d][l]  (fp32, small) --
__global__ __launch_bounds__(256)
void wcomb_k(const float* __restrict__ A, const float* __restrict__ Wall,
             float* __restrict__ C)
{
  constexpr int T=256;
  __shared__ float As[32][68];
  __shared__ float Ws[32][132];
  const int tid = threadIdx.x;
  const int m0 = blockIdx.x*64, n0 = blockIdx.y*128;
  const float* W = Wall + (size_t)(m0>>9)*DS*DL;
  const int ty = tid>>4, tx = tid&15;
  float4 pa[2], pw[4];
  auto loadA = [&](int k0){
    #pragma unroll
    for(int it=0; it<2; ++it){
      int v = tid + T*it; int rr = v>>3, c4 = v&7;
      pa[it] = *(const float4*)(A + (size_t)(m0+rr)*DS + k0 + (c4<<2));
    }
  };
  auto loadW = [&](int k0){
    #pragma unroll
    for(int it=0; it<4; ++it){
      int v = tid + T*it; int rr = v>>5, c4 = v&31;
      pw[it] = *(const float4*)(W + (size_t)(k0+rr)*DL + n0 + (c4<<2));
    }
  };
  float acc[4][8];
  #pragma unroll
  for(int i=0;i<4;i++)
    #pragma unroll
    for(int j=0;j<8;j++) acc[i][j]=0.f;
  loadA(0); loadW(0);
  for(int k0=0; k0<DS; k0+=32){
    __syncthreads();
    #pragma unroll
    for(int it=0; it<2; ++it){
      int v = tid + T*it; int rr=v>>3, c4=v&7;
      As[(c4<<2)+0][rr]=pa[it].x; As[(c4<<2)+1][rr]=pa[it].y;
      As[(c4<<2)+2][rr]=pa[it].z; As[(c4<<2)+3][rr]=pa[it].w;
    }
    #pragma unroll
    for(int it=0; it<4; ++it){
      int v = tid + T*it; int rr=v>>5, c4=v&31;
      *(float4*)&Ws[rr][c4<<2] = pw[it];
    }
    __syncthreads();
    if(k0+32 < DS){ loadA(k0+32); loadW(k0+32); }
    #pragma unroll
    for(int kk=0; kk<32; kk++){
      float4 a4 = *(const float4*)&As[kk][ty<<2];
      float4 b0 = *(const float4*)&Ws[kk][tx<<2];
      float4 b1 = *(const float4*)&Ws[kk][64+(tx<<2)];
      float a[4]={a4.x,a4.y,a4.z,a4.w};
      float b[8]={b0.x,b0.y,b0.z,b0.w,b1.x,b1.y,b1.z,b1.w};
      #pragma unroll
      for(int i=0;i<4;i++)
        #pragma unroll
        for(int j=0;j<8;j++) acc[i][j] = fmaf(a[i], b[j], acc[i][j]);
    }
  }
  #pragma unroll
  for(int i=0;i<4;i++){
    int m = m0 + (ty<<2) + i;
    #pragma unroll
    for(int j=0;j<8;j++){
      int n = n0 + ((j<4)? (tx<<2)+j : 64+(tx<<2)+(j-4));
      C[((size_t)m<<9)+n] = acc[i][j];
    }
  }
}

// --- init: active=1, msg={1,0..}, cons=0, relc slot0 = qry_b ---------------
__global__ void init_k(int* __restrict__ msg, int* __restrict__ act,
                       float* __restrict__ relc, const float* __restrict__ qb,
                       int* __restrict__ cons){
  int i = blockIdx.x*256 + threadIdx.x;
  if(i < TOK){
    act[i] = 1;
    #pragma unroll
    for(int nn=0;nn<4;nn++) relc[nn*TOK + i] = qb[nn];
  }
  if(i < 32){ msg[i] = (i==0) ? 1 : 0; cons[i] = 0; }
}

// --- combined quantizer bias: b2 = sym_b.cb - 0.5|cb|^2 --------------------
__global__ void bias2_k(const float* __restrict__ cb, const float* __restrict__ sb,
                        float* __restrict__ b2){
  int row = blockIdx.x*4 + (threadIdx.x>>6);
  int lane = threadIdx.x&63;
  const float* cv = cb + ((size_t)row<<7);
  const float* sbn = sb + ((row>>9)<<7);
  float c0=cv[lane], c1=cv[lane+64];
  float nrm = c0*c0 + c1*c1;
  float dt  = c0*sbn[lane] + c1*sbn[lane+64];
  nrm = wsum(nrm); dt = wsum(dt);
  if(lane==0) b2[row] = dt - 0.5f*nrm;
}

// --- halting / update / rel-cache append / mask-fold -----------------------
__global__ void mupdate_k(const float* __restrict__ no_, float* __restrict__ out,
                          f16* __restrict__ outh, f16* __restrict__ outl,
                          float* __restrict__ relc, const int* __restrict__ idx,
                          const float* __restrict__ cbn, const float* __restrict__ qw,
                          const float* __restrict__ qb, int* __restrict__ act,
                          int* __restrict__ cons, int* __restrict__ msg,
                          int t, int ptr, int pe){
  int m = blockIdx.x*4 + (threadIdx.x>>6);
  int lane = threadIdx.x&63;
  const float* nrow = no_ + ((size_t)m<<9);
  float* orow = out + ((size_t)m<<9);
  float nv[8]; float s=0.f;
  #pragma unroll
  for(int rr=0;rr<8;rr++){
    int c = lane + (rr<<6);
    nv[rr]=nrow[c];
    float d = nv[rr]-orow[c]; s += d*d;
  }
  s = wsum(s);
  float delta = sqrtf(s);
  int a = act[m];
  int halt = (delta < 1e-3f) && a;
  int assigned = (t>0) ? a : 1;
  int upd = assigned && !halt;
  if(lane==0) act[m] = a && !halt;
  if(upd){
    #pragma unroll
    for(int rr=0;rr<8;rr++){
      int c = lane + (rr<<6);
      float v = nv[rr];
      orow[c] = v;
      f16 h = (f16)v;
      outh[((size_t)m<<9)+c] = h;
      outl[((size_t)m<<9)+c] = (f16)((v-(float)h)*2048.0f);
    }
  }
  if(ptr >= 0){
    const float* qv = cbn + ((size_t)idx[m]<<7);
    float q0=qv[lane], q1=qv[lane+64];
    #pragma unroll
    for(int nn=0;nn<4;nn++){
      float pr = q0*qw[(nn<<7)+lane] + q1*qw[(nn<<7)+64+lane];
      pr = wsum(pr);
      if(lane==0) relc[(size_t)((ptr<<2)+nn)*TOK + m] = pr + qb[nn];
    }
  }
  if(pe >= 0 && blockIdx.x==0 && threadIdx.x < 32){
    int s2 = threadIdx.x;
    msg[s2] = (s2 < pe) && !cons[s2];
    cons[s2] = 0;
  }
}

} // namespace

extern "C" void kernel_launch(void* const* d_in, const int* in_sizes, int n_in,
                              void* d_out, int out_size, void* d_ws, size_t ws_size,
                              hipStream_t stream)
{
  (void)in_sizes; (void)n_in; (void)out_size; (void)ws_size;
  const float* x   = (const float*)d_in[0];
  const float* ipw = (const float*)d_in[1];
  const float* ipb = (const float*)d_in[2];
  const float* tp  = (const float*)d_in[3];
  const float* sw  = (const float*)d_in[4];
  const float* sb  = (const float*)d_in[5];
  const float* qw  = (const float*)d_in[6];
  const float* qb  = (const float*)d_in[7];
  const float* rw  = (const float*)d_in[8];
  const float* rb  = (const float*)d_in[9];
  const float* c1w = (const float*)d_in[10];
  const float* c1b = (const float*)d_in[11];
  const float* c2w = (const float*)d_in[12];
  const float* c2b = (const float*)d_in[13];
  const float* cb  = (const float*)d_in[14];
  float* out = (float*)d_out;

  char* p = (char*)d_ws;
  auto alloc = [&](size_t b)->char*{ char* r=p; p += (b+255)&~(size_t)255; return r; };
  f16* slabh = (f16*)alloc((size_t)NSLOT*TOK*DL*2);
  f16* slabl = (f16*)alloc((size_t)NSLOT*TOK*DL*2);
  f16* outh  = (f16*)alloc((size_t)TOK*DL*2);
  f16* outl  = (f16*)alloc((size_t)TOK*DL*2);
  f16* zh    = (f16*)alloc((size_t)TOK*DL*2);
  f16* zl    = (f16*)alloc((size_t)TOK*DL*2);
  f16* hh    = (f16*)alloc((size_t)TOK*DL*2);
  f16* hl    = (f16*)alloc((size_t)TOK*DL*2);
  float* sn  = (float*)alloc((size_t)TOK*DL*4);      // nodeo fp32 + wcomb staging
  f16* rwh   = (f16*)alloc((size_t)4*DL*1024*2);
  f16* rwl   = (f16*)alloc((size_t)4*DL*1024*2);
  f16* c1h   = (f16*)alloc((size_t)4*DL*640*2);
  f16* c1l   = (f16*)alloc((size_t)4*DL*640*2);
  f16* c2h   = (f16*)alloc((size_t)4*DL*DL*2);
  f16* c2l   = (f16*)alloc((size_t)4*DL*DL*2);
  f16* wch   = (f16*)alloc((size_t)4*NC*DL*2);
  f16* wcl   = (f16*)alloc((size_t)4*NC*DL*2);
  f16* iph   = (f16*)alloc((size_t)DL*DL*2);
  f16* ipl   = (f16*)alloc((size_t)DL*DL*2);
  f16* cbh   = (f16*)alloc((size_t)4*NC*DS*2);
  f16* cbl   = (f16*)alloc((size_t)4*NC*DS*2);
  f16* bch   = (f16*)alloc((size_t)4*TOK*DL*2);      // packed bus ctx (4 nodes)
  f16* bcl   = (f16*)alloc((size_t)4*TOK*DL*2);
  float* b2  = (float*)alloc(4*NC*4);
  float* relc= (float*)alloc((size_t)NSLOT*4*TOK*4);
  float* scpv= (float*)alloc((size_t)8*TOK*4);
  int* scpi  = (int*)alloc((size_t)8*TOK*4);
  int* idxb  = (int*)alloc(TOK*4);
  int* act   = (int*)alloc(TOK*4);
  int* msg   = (int*)alloc(256);
  int* cons  = (int*)alloc(256);

  dim3 G(64,8), B(256);

  init_k<<<16,256,0,stream>>>(msg, act, relc, qb, cons);
  bias2_k<<<512,256,0,stream>>>(cb, sb, b2);
  wcomb_k<<<dim3(32,4),B,0,stream>>>(cb, sw, sn);
  split_k<<<2048,256,0,stream>>>(x, hh, hl, TOK*DL);   // x planes staged in hh/hl
  SplitArgs5 sa;
  sa.a[0] = { ipw, iph, ipl, DL*DL };
  sa.a[1] = { rw,  rwh, rwl, 4*DL*1024 };
  sa.a[2] = { c1w, c1h, c1l, 4*DL*640 };
  sa.a[3] = { c2w, c2h, c2l, 4*DL*DL };
  sa.a[4] = { cb,  cbh, cbl, 4*NC*DS };
  splitm_k<<<2048,256,0,stream>>>(sa);
  split_k<<<1024,256,0,stream>>>(sn, wch, wcl, 4*NC*DL);

  // input projection + prompts -> out(fp32)+planes, slab slot0 planes
  mgemm<0,4><<<G,B,0,stream>>>(hh,hl, nullptr,nullptr, iph,ipl,
      ipb, tp, out, outh,outl, slabh,slabl,
      nullptr,nullptr,nullptr, DL, DL);

  int ptr = 1;
  for(int t=0;t<4;t++){
    int pt = 1 + 4*t;
    // pack all 4 nodes' bus contexts for this op (same snapshot for all)
    buspack_k<<<1024,256,0,stream>>>(relc, msg, slabh, slabl, bch, bcl, cons, pt);
    for(int n=0;n<4;n++){
      // z_read = [out | busctx[n]] @ read_w^T + read_b   (contiguous A2)
      mgemm<1,0><<<G,B,0,stream>>>(outh,outl,
          bch+(size_t)n*TOK*DL, bcl+(size_t)n*TOK*DL,
          rwh+(size_t)n*DL*1024, rwl+(size_t)n*DL*1024, rb+(size_t)n*DL,
          nullptr, nullptr, zh,zl, nullptr,nullptr,
          nullptr,nullptr,nullptr, 1024, 512);
      // scores -> block-partial argmax (fused codemax part 1)
      mgemm<0,1><<<G,B,0,stream>>>(zh,zl, nullptr,nullptr,
          wch+(size_t)n*NC*DL, wcl+(size_t)n*NC*DL, b2+(size_t)n*NC,
          nullptr, nullptr, nullptr,nullptr, nullptr,nullptr,
          scpv,scpi,nullptr, 512, 512);
      // hid = relu([z_read | cb[idx]] @ c1_w^T + c1_b)  (fused codemax finalize)
      mgemm<2,2><<<G,B,0,stream>>>(zh,zl, cbh+(size_t)n*NC*DS, cbl+(size_t)n*NC*DS,
          c1h+(size_t)n*DL*640, c1l+(size_t)n*DL*640, c1b+(size_t)n*DL,
          nullptr, nullptr, hh,hl, nullptr,nullptr,
          scpv,scpi,idxb, 640, 512);
      // node_out = hid @ c2_w^T + c2_b + out ; slab planes via C2 (t<3)
      f16* sph = (t<3) ? slabh + ((size_t)ptr<<21) : nullptr;
      f16* spl = (t<3) ? slabl + ((size_t)ptr<<21) : nullptr;
      mgemm<0,3><<<G,B,0,stream>>>(hh,hl, nullptr,nullptr,
          c2h+(size_t)n*DL*DL, c2l+(size_t)n*DL*DL, c2b+(size_t)n*DL,
          out, sn, nullptr,nullptr, sph,spl,
          nullptr,nullptr,nullptr, 512, 512);
      // halting / selective update / rel cache / mask fold
      mupdate_k<<<1024,256,0,stream>>>(sn, out, outh,outl, relc, idxb,
          cb+(size_t)n*NC*DS, qw, qb, act, cons, msg, t,
          (t<3)? ptr : -1, (n==3 && t<3)? (1+4*(t+1)) : -1);
      ptr++;
    }
  }
}

// Round 14
// 1276.751 us; speedup vs baseline: 1.5642x; 1.0330x over previous
//
#include <hip/hip_runtime.h>
#include <math.h>

namespace {

typedef _Float16 f16;
typedef __attribute__((ext_vector_type(8))) _Float16 f16x8;
typedef __attribute__((ext_vector_type(4))) float f32x4;

constexpr int TOK = 4096;
constexpr int DL  = 512;
constexpr int DS  = 128;
constexpr int NC  = 512;
constexpr int NSLOT = 13;

__device__ __forceinline__ float wsum(float v){
  #pragma unroll
  for(int o=32;o>0;o>>=1) v += __shfl_xor(v,o);
  return v;
}

__device__ __forceinline__ void gload16(const void* g, void* l){
  __builtin_amdgcn_global_load_lds(
      (const __attribute__((address_space(1))) unsigned int*)g,
      (__attribute__((address_space(3))) unsigned int*)l, 16, 0, 0);
}

// byte offset of the 16B slot holding (row, 16B-granule g) — bank-spread bijection
__device__ __forceinline__ int slotb(int row, int g){
  return (((row ^ ((row>>2)&1))<<2) | (g ^ (row&3))) << 4;
}

// ===========================================================================
// fp16x2-split MFMA GEMM, BM=64 BN=64 BK=32, 4 waves (each a 32x32 tile).
// Grid (64,8), 2 blocks/CU. 3-buffer pipeline, counted s_waitcnt vmcnt(4).
// AMODE: 0 plain
//        1 concat [A1 | slab[gsel[m]]], gsel from FUSED bus-argmax (relmax)
//        3 plain staging + FUSED codemax finalize (gsel for EPI=5's pq row)
// EPI: 0 planes (zread) ; 1 score block-partial argmax (no C write)
//      3 fp32 + fp32-res (+slab planes via C2) (nodeo)
//      4 fp32 + prompt + planes + slab0 planes (input)
//      5 planes + relu + pq[gsel[row]] row add (hid; K=512, quant via table)
// ldb decouples B row stride from K (hid: rows are 640 long, K=512).
// ===========================================================================
template<int AMODE,int EPI>
__global__ __launch_bounds__(256,2) void mgemm(
    const f16* __restrict__ A1h, const f16* __restrict__ A1l,
    const f16* __restrict__ A2h, const f16* __restrict__ A2l,
    const f16* __restrict__ Bh, const f16* __restrict__ Bl,
    const float* __restrict__ bias, const float* __restrict__ res,
    float* __restrict__ Cf, f16* __restrict__ Ch, f16* __restrict__ Cl,
    f16* __restrict__ C2h, f16* __restrict__ C2l,
    float* __restrict__ scpv, int* __restrict__ scpi, int* __restrict__ idxg,
    const float* __restrict__ relc, const int* __restrict__ msg,
    int* __restrict__ cons, int pt, int node,
    const float* __restrict__ pq,
    int K, int K0, int ldb)
{
  constexpr int SMB = 16384;  // Ah 4K | Al 4K | Bh 4K | Bl 4K
  __shared__ __align__(16) char smem[3*SMB];
  __shared__ int gsel[64];
  __shared__ float redv[4][32];
  __shared__ int   redi[4][32];
  const int tid = threadIdx.x, w = tid>>6, l = tid&63;
  const int m0 = blockIdx.x*64, n0 = blockIdx.y*64;
  const int NK = K>>5, SW = K0>>5;

  // ---- fused bus-argmax (relmax): per-row argmax over snapshot slots ------
  if(AMODE==1){
    if(tid<64){
      int m = m0+tid;
      float best = -1e9f; int bs = 0;
      for(int s=0;s<pt;s++){
        float v = msg[s] ? relc[(size_t)((s<<2)+node)*TOK + m] : -1e9f;
        if(v > best){ best=v; bs=s; }
      }
      gsel[tid]=bs;
      cons[bs]=1;                      // benign duplicate stores of 1 (x8 y-blocks)
    }
    __syncthreads();
  }
  // ---- fused code-argmax finalize (reads 8 block-partials, ascending y) ----
  if(AMODE==3){
    if(tid<64){
      int m = m0+tid;
      float bv = -INFINITY; int bi = 0;
      #pragma unroll
      for(int y=0;y<8;y++){
        float v = scpv[(size_t)y*TOK + m];
        if(v > bv){ bv=v; bi=scpi[(size_t)y*TOK + m]; }
      }
      gsel[tid]=bi;
      idxg[m]=bi;                      // duplicate identical writes across y-blocks
    }
    __syncthreads();
  }

  // ---- staging setup: 16 chunks of 1KB per K-step; wave w owns [4w,4w+4) ---
  const f16* sp[4]; const f16* sp2[4]; int loff[4];
  #pragma unroll
  for(int i=0;i<4;i++){
    int c = 4*w+i;
    int isA = (c<8);
    int plane = isA ? (c>>2) : ((c-8)>>2);
    int cidx  = isA ? (c&3)  : ((c-8)&3);
    loff[i] = (isA?0:8192) + plane*4096 + cidx*1024;
    int s = (cidx<<6) + l;
    int rp = s>>2, row = rp ^ ((rp>>2)&1), g = (s&3) ^ (row&3);  // inverse slotb
    int g8 = g<<3;
    if(isA){
      int m = m0 + row;
      const f16* p1 = (plane? A1l : A1h) + ((size_t)m<<9) + g8;
      sp[i] = p1;
      if(AMODE==1) sp2[i] = (plane? A2l : A2h) + ((size_t)gsel[row]<<21) + ((size_t)m<<9) + g8;
      else         sp2[i] = p1;
    } else {
      sp[i] = (plane? Bl : Bh) + (size_t)(n0+row)*ldb + g8;
      sp2[i] = sp[i];
    }
  }

  const int wr = w>>1, wc = w&1, q = l>>4, r = l&15;
  int aoff[2], boff[2];
  #pragma unroll
  for(int i=0;i<2;i++) aoff[i] = slotb(32*wr + 16*i + r, q);
  #pragma unroll
  for(int j=0;j<2;j++) boff[j] = 8192 + slotb(32*wc + 16*j + r, q);

  f32x4 acc1[2][2] = {}, acc2[2][2] = {};

  // advance staging pointers to step snext (handles part1->part2 switch)
  auto advance = [&](int snext){
    #pragma unroll
    for(int i=0;i<4;i++){
      if(AMODE==1 && (4*w+i)<8 && snext==SW) sp[i] = sp2[i];
      else                                    sp[i] += 32;
    }
  };

  // ---- prologue: stage steps 0 and 1 (NK >= 16 always here) ----
  #pragma unroll
  for(int i=0;i<4;i++) gload16(sp[i], smem + loff[i]);
  advance(1);
  #pragma unroll
  for(int i=0;i<4;i++) gload16(sp[i], smem + SMB + loff[i]);
  advance(2);
  asm volatile("s_waitcnt vmcnt(4)" ::: "memory");   // step-0 loads done
  __builtin_amdgcn_s_barrier();

  int roff = 0, soff = 2*SMB;
  for(int kt=0; kt<NK; ++kt){
    const char* Lb = smem + roff;
    f16x8 ah[2], al[2], bh[2], bl[2];
    #pragma unroll
    for(int i=0;i<2;i++){
      ah[i] = *(const f16x8*)(Lb + aoff[i]);
      al[i] = *(const f16x8*)(Lb + 4096 + aoff[i]);
    }
    #pragma unroll
    for(int j=0;j<2;j++){
      bh[j] = *(const f16x8*)(Lb + boff[j]);
      bl[j] = *(const f16x8*)(Lb + 4096 + boff[j]);
    }
    if(kt+2 < NK){
      #pragma unroll
      for(int i=0;i<4;i++) gload16(sp[i], smem + soff + loff[i]);
      advance(kt+3);
    }
    #pragma unroll
    for(int i=0;i<2;i++)
      #pragma unroll
      for(int j=0;j<2;j++){
        acc1[i][j] = __builtin_amdgcn_mfma_f32_16x16x32_f16(ah[i], bh[j], acc1[i][j], 0,0,0);
        acc2[i][j] = __builtin_amdgcn_mfma_f32_16x16x32_f16(ah[i], bl[j], acc2[i][j], 0,0,0);
        acc2[i][j] = __builtin_amdgcn_mfma_f32_16x16x32_f16(al[i], bh[j], acc2[i][j], 0,0,0);
      }
    if(kt+2 < NK){
      asm volatile("s_waitcnt vmcnt(4)" ::: "memory");
      __builtin_amdgcn_s_barrier();
    } else if(kt+1 < NK){
      asm volatile("s_waitcnt vmcnt(0)" ::: "memory");  // tail: drain last stage
      __builtin_amdgcn_s_barrier();
    }
    roff = (roff==2*SMB)? 0 : roff+SMB;
    soff = (soff==2*SMB)? 0 : soff+SMB;
  }

  if(EPI!=1){
    #pragma unroll
    for(int i=0;i<2;i++)
      #pragma unroll
      for(int j=0;j<2;j++)
        #pragma unroll
        for(int rr=0;rr<4;rr++){
          int lrow = 32*wr + 16*i + 4*q + rr;
          int rowm = m0 + lrow;
          int coln = n0 + 32*wc + 16*j + r;
          size_t o = ((size_t)rowm<<9) + coln;
          float v = acc1[i][j][rr] + acc2[i][j][rr]*(1.0f/2048.0f) + bias[coln];
          if(EPI==5){ v += pq[((size_t)gsel[lrow]<<9) + coln]; v = fmaxf(v, 0.f); }
          if(EPI==3) v += res[o];
          if(EPI==4) v += res[(((size_t)(rowm&255))<<9) + coln];
          if(EPI==3 || EPI==4) Cf[o] = v;
          if(EPI==0 || EPI==4 || EPI==5){
            f16 h = (f16)v;
            Ch[o] = h; Cl[o] = (f16)((v-(float)h)*2048.0f);
          }
          if((EPI==3 || EPI==4) && C2h){
            f16 h = (f16)v;
            C2h[o] = h; C2l[o] = (f16)((v-(float)h)*2048.0f);
          }
        }
  } else {
    // block-partial argmax over this block's 64 cols, exact first-index ties
    #pragma unroll
    for(int i=0;i<2;i++)
      #pragma unroll
      for(int rr=0;rr<4;rr++){
        float v0 = acc1[i][0][rr] + acc2[i][0][rr]*(1.0f/2048.0f) + bias[n0+32*wc+r];
        float v1 = acc1[i][1][rr] + acc2[i][1][rr]*(1.0f/2048.0f) + bias[n0+32*wc+16+r];
        float bv; int bc;
        if(v1 > v0){ bv=v1; bc=n0+32*wc+16+r; } else { bv=v0; bc=n0+32*wc+r; }
        #pragma unroll
        for(int o=1;o<16;o<<=1){
          float ov = __shfl_xor(bv,o); int oi = __shfl_xor(bc,o);
          if(ov>bv || (ov==bv && oi<bc)){ bv=ov; bc=oi; }
        }
        if(r==0){ redv[w][16*i+4*q+rr]=bv; redi[w][16*i+4*q+rr]=bc; }
      }
    __syncthreads();
    if(tid<64){
      int wr2 = tid>>5, li = tid&31;
      float bv = redv[2*wr2][li]; int bc = redi[2*wr2][li];
      float ov = redv[2*wr2+1][li]; int oi = redi[2*wr2+1][li];
      if(ov>bv || (ov==bv && oi<bc)){ bv=ov; bc=oi; }
      scpv[(size_t)blockIdx.y*TOK + m0 + tid] = bv;
      scpi[(size_t)blockIdx.y*TOK + m0 + tid] = bc;
    }
  }
}

// --- fp32 -> (hi, lo*2048) split -------------------------------------------
__global__ void split_k(const float* __restrict__ src, f16* __restrict__ hi,
                        f16* __restrict__ lo, int n){
  for(int i = blockIdx.x*256 + threadIdx.x; i < n; i += gridDim.x*256){
    float v = src[i];
    f16 h = (f16)v;
    hi[i] = h;
    lo[i] = (f16)((v - (float)h)*2048.0f);
  }
}

// --- batched weight split: 5 segments in one dispatch ----------------------
struct SplitArg { const float* src; f16* hi; f16* lo; int n; };
struct SplitArgs5 { SplitArg a[5]; };
__global__ void splitm_k(SplitArgs5 A){
  int stride = gridDim.x*256;
  #pragma unroll
  for(int s=0;s<5;s++){
    const float* src = A.a[s].src; f16* hi = A.a[s].hi; f16* lo = A.a[s].lo;
    int n = A.a[s].n;
    for(int i = blockIdx.x*256 + threadIdx.x; i < n; i += stride){
      float v = src[i];
      f16 h = (f16)v;
      hi[i] = h;
      lo[i] = (f16)((v - (float)h)*2048.0f);
    }
  }
}

// --- wcomb[n*512+c][l] = sum_d cb[n][c][d] * sym_w[n][d][l]  (fp32) --------
__global__ __launch_bounds__(256)
void wcomb_k(const float* __restrict__ A, const float* __restrict__ Wall,
             float* __restrict__ C)
{
  constexpr int T=256;
  __shared__ float As[32][68];
  __shared__ float Ws[32][132];
  const int tid = threadIdx.x;
  const int m0 = blockIdx.x*64, n0 = blockIdx.y*128;
  const float* W = Wall + (size_t)(m0>>9)*DS*DL;
  const int ty = tid>>4, tx = tid&15;
  float4 pa[2], pw[4];
  auto loadA = [&](int k0){
    #pragma unroll
    for(int it=0; it<2; ++it){
      int v = tid + T*it; int rr = v>>3, c4 = v&7;
      pa[it] = *(const float4*)(A + (size_t)(m0+rr)*DS + k0 + (c4<<2));
    }
  };
  auto loadW = [&](int k0){
    #pragma unroll
    for(int it=0; it<4; ++it){
      int v = tid + T*it; int rr = v>>5, c4 = v&31;
      pw[it] = *(const float4*)(W + (size_t)(k0+rr)*DL + n0 + (c4<<2));
    }
  };
  float acc[4][8];
  #pragma unroll
  for(int i=0;i<4;i++)
    #pragma unroll
    for(int j=0;j<8;j++) acc[i][j]=0.f;
  loadA(0); loadW(0);
  for(int k0=0; k0<DS; k0+=32){
    __syncthreads();
    #pragma unroll
    for(int it=0; it<2; ++it){
      int v = tid + T*it; int rr=v>>3, c4=v&7;
      As[(c4<<2)+0][rr]=pa[it].x; As[(c4<<2)+1][rr]=pa[it].y;
      As[(c4<<2)+2][rr]=pa[it].z; As[(c4<<2)+3][rr]=pa[it].w;
    }
    #pragma unroll
    for(int it=0; it<4; ++it){
      int v = tid + T*it; int rr=v>>5, c4=v&31;
      *(float4*)&Ws[rr][c4<<2] = pw[it];
    }
    __syncthreads();
    if(k0+32 < DS){ loadA(k0+32); loadW(k0+32); }
    #pragma unroll
    for(int kk=0; kk<32; kk++){
      float4 a4 = *(const float4*)&As[kk][ty<<2];
      float4 b0 = *(const float4*)&Ws[kk][tx<<2];
      float4 b1 = *(const float4*)&Ws[kk][64+(tx<<2)];
      float a[4]={a4.x,a4.y,a4.z,a4.w};
      float b[8]={b0.x,b0.y,b0.z,b0.w,b1.x,b1.y,b1.z,b1.w};
      #pragma unroll
      for(int i=0;i<4;i++)
        #pragma unroll
        for(int j=0;j<8;j++) acc[i][j] = fmaf(a[i], b[j], acc[i][j]);
    }
  }
  #pragma unroll
  for(int i=0;i<4;i++){
    int m = m0 + (ty<<2) + i;
    #pragma unroll
    for(int j=0;j<8;j++){
      int n = n0 + ((j<4)? (tx<<2)+j : 64+(tx<<2)+(j-4));
      C[((size_t)m<<9)+n] = acc[i][j];
    }
  }
}

// --- pq[n][c][o] = sum_d cb[n][c][d] * c1w[n][o][512+d]  (fp32 NT GEMM) ----
__global__ __launch_bounds__(256)
void prequant_k(const float* __restrict__ cbp, const float* __restrict__ c1wp,
                float* __restrict__ pq)
{
  constexpr int T=256;
  __shared__ float As[32][68];
  __shared__ float Ws[32][132];
  const int tid = threadIdx.x;
  const int nz = blockIdx.z;
  const int m0 = blockIdx.x*64, n0 = blockIdx.y*128;
  const float* A = cbp  + (size_t)nz*NC*DS;          // [512 codes][128]
  const float* W = c1wp + (size_t)nz*DL*640 + 512;   // rows o (stride 640), quant cols
  float* C = pq + (size_t)nz*NC*DL;
  const int ty = tid>>4, tx = tid&15;
  float4 pa[2], pw[4];
  auto loadA = [&](int k0){
    #pragma unroll
    for(int it=0; it<2; ++it){
      int v = tid + T*it; int rr = v>>3, c4 = v&7;
      pa[it] = *(const float4*)(A + (size_t)(m0+rr)*DS + k0 + (c4<<2));
    }
  };
  auto loadW = [&](int k0){
    #pragma unroll
    for(int it=0; it<4; ++it){
      int v = tid + T*it; int rr = v>>3, c4 = v&7;
      pw[it] = *(const float4*)(W + (size_t)(n0+rr)*640 + k0 + (c4<<2));
    }
  };
  float acc[4][8];
  #pragma unroll
  for(int i=0;i<4;i++)
    #pragma unroll
    for(int j=0;j<8;j++) acc[i][j]=0.f;
  loadA(0); loadW(0);
  for(int k0=0; k0<DS; k0+=32){
    __syncthreads();
    #pragma unroll
    for(int it=0; it<2; ++it){
      int v = tid + T*it; int rr=v>>3, c4=v&7;
      As[(c4<<2)+0][rr]=pa[it].x; As[(c4<<2)+1][rr]=pa[it].y;
      As[(c4<<2)+2][rr]=pa[it].z; As[(c4<<2)+3][rr]=pa[it].w;
    }
    #pragma unroll
    for(int it=0; it<4; ++it){
      int v = tid + T*it; int rr=v>>3, c4=v&7;
      Ws[(c4<<2)+0][rr]=pw[it].x; Ws[(c4<<2)+1][rr]=pw[it].y;
      Ws[(c4<<2)+2][rr]=pw[it].z; Ws[(c4<<2)+3][rr]=pw[it].w;
    }
    __syncthreads();
    if(k0+32 < DS){ loadA(k0+32); loadW(k0+32); }
    #pragma unroll
    for(int kk=0; kk<32; kk++){
      float4 a4 = *(const float4*)&As[kk][ty<<2];
      float4 b0 = *(const float4*)&Ws[kk][tx<<2];
      float4 b1 = *(const float4*)&Ws[kk][64+(tx<<2)];
      float a[4]={a4.x,a4.y,a4.z,a4.w};
      float b[8]={b0.x,b0.y,b0.z,b0.w,b1.x,b1.y,b1.z,b1.w};
      #pragma unroll
      for(int i=0;i<4;i++)
        #pragma unroll
        for(int j=0;j<8;j++) acc[i][j] = fmaf(a[i], b[j], acc[i][j]);
    }
  }
  #pragma unroll
  for(int i=0;i<4;i++){
    int m = m0 + (ty<<2) + i;
    #pragma unroll
    for(int j=0;j<8;j++){
      int n = n0 + ((j<4)? (tx<<2)+j : 64+(tx<<2)+(j-4));
      C[((size_t)m<<9)+n] = acc[i][j];
    }
  }
}

// --- init: active=1, msg={1,0..}, cons=0, relc slot0 = qry_b ---------------
__global__ void init_k(int* __restrict__ msg, int* __restrict__ act,
                       float* __restrict__ relc, const float* __restrict__ qb,
                       int* __restrict__ cons){
  int i = blockIdx.x*256 + threadIdx.x;
  if(i < TOK){
    act[i] = 1;
    #pragma unroll
    for(int nn=0;nn<4;nn++) relc[nn*TOK + i] = qb[nn];
  }
  if(i < 32){ msg[i] = (i==0) ? 1 : 0; cons[i] = 0; }
}

// --- combined quantizer bias: b2 = sym_b.cb - 0.5|cb|^2 --------------------
__global__ void bias2_k(const float* __restrict__ cb, const float* __restrict__ sb,
                        float* __restrict__ b2){
  int row = blockIdx.x*4 + (threadIdx.x>>6);
  int lane = threadIdx.x&63;
  const float* cv = cb + ((size_t)row<<7);
  const float* sbn = sb + ((row>>9)<<7);
  float c0=cv[lane], c1=cv[lane+64];
  float nrm = c0*c0 + c1*c1;
  float dt  = c0*sbn[lane] + c1*sbn[lane+64];
  nrm = wsum(nrm); dt = wsum(dt);
  if(lane==0) b2[row] = dt - 0.5f*nrm;
}

// --- halting / update / rel-cache append / mask-fold -----------------------
__global__ void mupdate_k(const float* __restrict__ no_, float* __restrict__ out,
                          f16* __restrict__ outh, f16* __restrict__ outl,
                          float* __restrict__ relc, const int* __restrict__ idx,
                          const float* __restrict__ cbn, const float* __restrict__ qw,
                          const float* __restrict__ qb, int* __restrict__ act,
                          int* __restrict__ cons, int* __restrict__ msg,
                          int t, int ptr, int pe){
  int m = blockIdx.x*4 + (threadIdx.x>>6);
  int lane = threadIdx.x&63;
  const float* nrow = no_ + ((size_t)m<<9);
  float* orow = out + ((size_t)m<<9);
  float nv[8]; float s=0.f;
  #pragma unroll
  for(int rr=0;rr<8;rr++){
    int c = lane + (rr<<6);
    nv[rr]=nrow[c];
    float d = nv[rr]-orow[c]; s += d*d;
  }
  s = wsum(s);
  float delta = sqrtf(s);
  int a = act[m];
  int halt = (delta < 1e-3f) && a;
  int assigned = (t>0) ? a : 1;
  int upd = assigned && !halt;
  if(lane==0) act[m] = a && !halt;
  if(upd){
    #pragma unroll
    for(int rr=0;rr<8;rr++){
      int c = lane + (rr<<6);
      float v = nv[rr];
      orow[c] = v;
      f16 h = (f16)v;
      outh[((size_t)m<<9)+c] = h;
      outl[((size_t)m<<9)+c] = (f16)((v-(float)h)*2048.0f);
    }
  }
  if(ptr >= 0){
    const float* qv = cbn + ((size_t)idx[m]<<7);
    float q0=qv[lane], q1=qv[lane+64];
    #pragma unroll
    for(int nn=0;nn<4;nn++){
      float pr = q0*qw[(nn<<7)+lane] + q1*qw[(nn<<7)+64+lane];
      pr = wsum(pr);
      if(lane==0) relc[(size_t)((ptr<<2)+nn)*TOK + m] = pr + qb[nn];
    }
  }
  if(pe >= 0 && blockIdx.x==0 && threadIdx.x < 32){
    int s2 = threadIdx.x;
    msg[s2] = (s2 < pe) && !cons[s2];
    cons[s2] = 0;
  }
}

} // namespace

extern "C" void kernel_launch(void* const* d_in, const int* in_sizes, int n_in,
                              void* d_out, int out_size, void* d_ws, size_t ws_size,
                              hipStream_t stream)
{
  (void)in_sizes; (void)n_in; (void)out_size; (void)ws_size;
  const float* x   = (const float*)d_in[0];
  const float* ipw = (const float*)d_in[1];
  const float* ipb = (const float*)d_in[2];
  const float* tp  = (const float*)d_in[3];
  const float* sw  = (const float*)d_in[4];
  const float* sb  = (const float*)d_in[5];
  const float* qw  = (const float*)d_in[6];
  const float* qb  = (const float*)d_in[7];
  const float* rw  = (const float*)d_in[8];
  const float* rb  = (const float*)d_in[9];
  const float* c1w = (const float*)d_in[10];
  const float* c1b = (const float*)d_in[11];
  const float* c2w = (const float*)d_in[12];
  const float* c2b = (const float*)d_in[13];
  const float* cb  = (const float*)d_in[14];
  float* out = (float*)d_out;

  char* p = (char*)d_ws;
  auto alloc = [&](size_t b)->char*{ char* r=p; p += (b+255)&~(size_t)255; return r; };
  f16* slabh = (f16*)alloc((size_t)NSLOT*TOK*DL*2);
  f16* slabl = (f16*)alloc((size_t)NSLOT*TOK*DL*2);
  f16* outh  = (f16*)alloc((size_t)TOK*DL*2);
  f16* outl  = (f16*)alloc((size_t)TOK*DL*2);
  f16* zh    = (f16*)alloc((size_t)TOK*DL*2);
  f16* zl    = (f16*)alloc((size_t)TOK*DL*2);
  f16* hh    = (f16*)alloc((size_t)TOK*DL*2);
  f16* hl    = (f16*)alloc((size_t)TOK*DL*2);
  float* sn  = (float*)alloc((size_t)TOK*DL*4);      // nodeo fp32 + wcomb staging
  f16* rwh   = (f16*)alloc((size_t)4*DL*1024*2);
  f16* rwl   = (f16*)alloc((size_t)4*DL*1024*2);
  f16* c1h   = (f16*)alloc((size_t)4*DL*640*2);
  f16* c1l   = (f16*)alloc((size_t)4*DL*640*2);
  f16* c2h   = (f16*)alloc((size_t)4*DL*DL*2);
  f16* c2l   = (f16*)alloc((size_t)4*DL*DL*2);
  f16* wch   = (f16*)alloc((size_t)4*NC*DL*2);
  f16* wcl   = (f16*)alloc((size_t)4*NC*DL*2);
  f16* iph   = (f16*)alloc((size_t)DL*DL*2);
  f16* ipl   = (f16*)alloc((size_t)DL*DL*2);
  f16* cbh   = (f16*)alloc((size_t)4*NC*DS*2);
  f16* cbl   = (f16*)alloc((size_t)4*NC*DS*2);
  float* pq  = (float*)alloc((size_t)4*NC*DL*4);     // quantizer-output table
  float* b2  = (float*)alloc(4*NC*4);
  float* relc= (float*)alloc((size_t)NSLOT*4*TOK*4);
  float* scpv= (float*)alloc((size_t)8*TOK*4);
  int* scpi  = (int*)alloc((size_t)8*TOK*4);
  int* idxb  = (int*)alloc(TOK*4);
  int* act   = (int*)alloc(TOK*4);
  int* msg   = (int*)alloc(256);
  int* cons  = (int*)alloc(256);

  dim3 G(64,8), B(256);

  init_k<<<16,256,0,stream>>>(msg, act, relc, qb, cons);
  bias2_k<<<512,256,0,stream>>>(cb, sb, b2);
  wcomb_k<<<dim3(32,4),B,0,stream>>>(cb, sw, sn);
  prequant_k<<<dim3(8,4,4),B,0,stream>>>(cb, c1w, pq);
  split_k<<<2048,256,0,stream>>>(x, hh, hl, TOK*DL);   // x planes staged in hh/hl
  SplitArgs5 sa;
  sa.a[0] = { ipw, iph, ipl, DL*DL };
  sa.a[1] = { rw,  rwh, rwl, 4*DL*1024 };
  sa.a[2] = { c1w, c1h, c1l, 4*DL*640 };
  sa.a[3] = { c2w, c2h, c2l, 4*DL*DL };
  sa.a[4] = { cb,  cbh, cbl, 4*NC*DS };
  splitm_k<<<2048,256,0,stream>>>(sa);
  split_k<<<1024,256,0,stream>>>(sn, wch, wcl, 4*NC*DL);

  // input projection + prompts -> out(fp32)+planes, slab slot0 planes
  mgemm<0,4><<<G,B,0,stream>>>(hh,hl, nullptr,nullptr, iph,ipl,
      ipb, tp, out, outh,outl, slabh,slabl,
      nullptr,nullptr,nullptr, nullptr,nullptr,nullptr, 0,0,
      nullptr, DL, DL, DL);

  int ptr = 1;
  for(int t=0;t<4;t++){
    int pt = 1 + 4*t;
    for(int n=0;n<4;n++){
      // z_read = [out | slab[top]] @ read_w^T + read_b   (fused relmax)
      mgemm<1,0><<<G,B,0,stream>>>(outh,outl, slabh,slabl,
          rwh+(size_t)n*DL*1024, rwl+(size_t)n*DL*1024, rb+(size_t)n*DL,
          nullptr, nullptr, zh,zl, nullptr,nullptr,
          nullptr,nullptr,nullptr, relc, msg, cons, pt, n,
          nullptr, 1024, 512, 1024);
      // scores -> block-partial argmax (fused codemax part 1)
      mgemm<0,1><<<G,B,0,stream>>>(zh,zl, nullptr,nullptr,
          wch+(size_t)n*NC*DL, wcl+(size_t)n*NC*DL, b2+(size_t)n*NC,
          nullptr, nullptr, nullptr,nullptr, nullptr,nullptr,
          scpv,scpi,nullptr, nullptr,nullptr,nullptr, 0,0,
          nullptr, 512, 512, 512);
      // hid = relu(z@c1w1^T + pq[idx] + c1b)   (K=512; quant via table)
      mgemm<3,5><<<G,B,0,stream>>>(zh,zl, nullptr,nullptr,
          c1h+(size_t)n*DL*640, c1l+(size_t)n*DL*640, c1b+(size_t)n*DL,
          nullptr, nullptr, hh,hl, nullptr,nullptr,
          scpv,scpi,idxb, nullptr,nullptr,nullptr, 0,0,
          pq+(size_t)n*NC*DL, 512, 512, 640);
      // node_out = hid @ c2_w^T + c2_b + out ; slab planes via C2 (t<3)
      f16* sph = (t<3) ? slabh + ((size_t)ptr<<21) : nullptr;
      f16* spl = (t<3) ? slabl + ((size_t)ptr<<21) : nullptr;
      mgemm<0,3><<<G,B,0,stream>>>(hh,hl, nullptr,nullptr,
          c2h+(size_t)n*DL*DL, c2l+(size_t)n*DL*DL, c2b+(size_t)n*DL,
          out, sn, nullptr,nullptr, sph,spl,
          nullptr,nullptr,nullptr, nullptr,nullptr,nullptr, 0,0,
          nullptr, 512, 512, 512);
      // halting / selective update / rel cache / mask fold
      mupdate_k<<<1024,256,0,stream>>>(sn, out, outh,outl, relc, idxb,
          cb+(size_t)n*NC*DS, qw, qb, act, cons, msg, t,
          (t<3)? ptr : -1, (n==3 && t<3)? (1+4*(t+1)) : -1);
      ptr++;
    }
  }
}